// Round 11
// baseline (300.009 us; speedup 1.0000x reference)
//
#include <hip/hip_runtime.h>
#include <hip/hip_fp16.h>
#include <hip/hip_bf16.h>
#include <math.h>

#define NB   8192
#define NENC 256
#define NC   25
#define NS   8192
#define SEL  26      // K+1
#define CAP  256
#define EPSA 1.25f   // |approx(f16) - true| d2 bound
#define ZSIG 2.2f
#define SLOTS 16     // per-(row,128-col-block) budget

typedef __attribute__((ext_vector_type(8))) short short8;
typedef __attribute__((ext_vector_type(4))) float f32x4;

__device__ __forceinline__ void gload_lds16(const void* g, void* l) {
  __builtin_amdgcn_global_load_lds(
      (const __attribute__((address_space(1))) unsigned int*)g,
      (__attribute__((address_space(3))) unsigned int*)l,
      16, 0, 0);
}
__device__ __forceinline__ float h2f(unsigned short u) {
  return __half2float(__ushort_as_half(u));
}

// ---- prep: e2, argmax, confidence, bf16 B, e2-moment atomics, zero ccount/flag ----
__global__ __launch_bounds__(256) void prep_kernel(
    const float* __restrict__ enc, const float* __restrict__ cat,
    float* __restrict__ e2, float* __restrict__ maxg, int* __restrict__ hard,
    ushort* __restrict__ Bbf, float* __restrict__ smoms,
    int* __restrict__ ccount, int* __restrict__ flag) {
  __shared__ float pr[8];
  int gt = blockIdx.x * 256 + threadIdx.x;
  int w = gt >> 6;
  int lane = gt & 63;

  if (gt < NS) { ccount[gt] = 0; flag[gt] = 0; }   // consumed by later dispatches

  float4 v = ((const float4*)(enc + (size_t)w * NENC))[lane];
  ushort4 o;
  __hip_bfloat16 h;
  h = __float2bfloat16(v.x); o.x = *(unsigned short*)&h;
  h = __float2bfloat16(v.y); o.y = *(unsigned short*)&h;
  h = __float2bfloat16(v.z); o.z = *(unsigned short*)&h;
  h = __float2bfloat16(v.w); o.w = *(unsigned short*)&h;
  ((ushort4*)(Bbf + (size_t)w * NENC))[lane] = o;

  float ss = v.x * v.x + v.y * v.y + v.z * v.z + v.w * v.w;
  #pragma unroll
  for (int ofs = 32; ofs; ofs >>= 1) ss += __shfl_down(ss, ofs, 64);

  float mv = -INFINITY;
  int mi = 0;
  if (lane < NC) { mv = cat[(size_t)w * NC + lane]; mi = lane; }
  #pragma unroll
  for (int ofs = 32; ofs; ofs >>= 1) {
    float ov = __shfl_down(mv, ofs, 64);
    int   oi = __shfl_down(mi, ofs, 64);
    if (ov > mv || (ov == mv && oi < mi)) { mv = ov; mi = oi; }
  }
  int wv = threadIdx.x >> 6;
  if (lane == 0) {
    e2[w] = ss; maxg[w] = mv; hard[w] = mi;
    pr[wv] = ss; pr[4 + wv] = ss * ss;
  }
  __syncthreads();
  if (threadIdx.x == 0) {
    atomicAdd(&smoms[0], pr[0] + pr[1] + pr[2] + pr[3]);
    atomicAdd(&smoms[1], pr[4] + pr[5] + pr[6] + pr[7]);
  }
}

// ---- thr: gather A (bf16), q2, per-row thresholds (analytic mu, no colmean term) ----
__global__ __launch_bounds__(256) void thr_kernel(
    const float* __restrict__ enc, const int* __restrict__ idxs,
    const float* __restrict__ e2, const float* __restrict__ smoms,
    ushort* __restrict__ Abf, float* __restrict__ q2,
    float* __restrict__ thr, float* __restrict__ thr2) {
  int gt = blockIdx.x * 256 + threadIdx.x;
  int s = gt >> 6, lane = gt & 63;
  int qi = idxs[s];
  float4 v = ((const float4*)(enc + (size_t)qi * NENC))[lane];
  ushort4 o;
  __hip_bfloat16 h;
  h = __float2bfloat16(v.x); o.x = *(unsigned short*)&h;
  h = __float2bfloat16(v.y); o.y = *(unsigned short*)&h;
  h = __float2bfloat16(v.z); o.z = *(unsigned short*)&h;
  h = __float2bfloat16(v.w); o.w = *(unsigned short*)&h;
  ((ushort4*)(Abf + (size_t)s * NENC))[lane] = o;

  if (lane == 0) {
    float q2v = e2[qi];
    float me2 = smoms[0] * (1.f / NB);
    float ve2 = smoms[1] * (1.f / NB) - me2 * me2;
    float mu  = q2v + me2;                 // qm term dropped: |2qm| <~ 1.5 << guard gap
    float sig = sqrtf(fmaxf(ve2 + 4.2f * q2v * (me2 / (float)NENC), 1e-3f));
    float tv  = mu - ZSIG * sig;
    q2[s]  = q2v;
    thr[s] = tv;
    if (tv > 0.f) {
      __half hf = __float2half_rd(tv);
      unsigned short hb = __half_as_ushort(hf);
      float mid = 0.5f * (__half2float(hf) + h2f((unsigned short)(hb + 1)));
      thr2[s] = mid;
    } else {
      thr2[s] = tv;
    }
  }
}

// ---- 128x128 bf16 MFMA GEMM (5 blk/CU) + LDS-aggregated candidate collect ----
__global__ __launch_bounds__(256, 5) void d2gemm(
    const ushort* __restrict__ Abf, const ushort* __restrict__ Bbf,
    const float* __restrict__ q2, const float* __restrict__ e2,
    const float* __restrict__ thr2, int* __restrict__ ccount,
    unsigned int* __restrict__ cand, int* __restrict__ flag) {
  __shared__ ushort lds[16384];   // A [0,8192) + B [8192,16384) : 32 KB

  const int t = threadIdx.x, lane = t & 63, w = t >> 6;
  int id = blockIdx.x;
  int wg = (id & 7) * 512 + (id >> 3);     // bijective XCD remap, nwg = 4096 = 8*512
  const int bm = wg >> 6, bn = wg & 63;
  const int wm = w >> 1, wn = w & 1;

  f32x4 acc[4][4];
  #pragma unroll
  for (int i = 0; i < 4; ++i)
    #pragma unroll
    for (int j = 0; j < 4; ++j) acc[i][j] = (f32x4){0.f, 0.f, 0.f, 0.f};

  const ushort* Ab = Abf + (size_t)(bm * 128) * NENC;
  const ushort* Bb = Bbf + (size_t)(bn * 128) * NENC;

  for (int kk = 0; kk < NENC; kk += 64) {
    if (kk) __syncthreads();
    #pragma unroll
    for (int u = 0; u < 4; ++u) {
      int flat = u * 256 + t;
      int r = flat >> 3, c = flat & 7;
      gload_lds16(Ab + (size_t)r * NENC + kk + ((c ^ (r & 7)) << 3),
                  (char*)lds + (u * 4 + w) * 1024);
    }
    #pragma unroll
    for (int u = 0; u < 4; ++u) {
      int flat = u * 256 + t;
      int r = flat >> 3, c = flat & 7;
      gload_lds16(Bb + (size_t)r * NENC + kk + ((c ^ (r & 7)) << 3),
                  (char*)lds + 16384 + (u * 4 + w) * 1024);
    }
    __syncthreads();

    #pragma unroll
    for (int kf = 0; kf < 2; ++kf) {
      short8 af[4], bg[4];
      int ch = kf * 4 + (lane >> 4);
      #pragma unroll
      for (int i = 0; i < 4; ++i) {
        int r = wm * 64 + i * 16 + (lane & 15);
        af[i] = *(const short8*)&lds[r * 64 + ((ch ^ (r & 7)) << 3)];
      }
      #pragma unroll
      for (int j = 0; j < 4; ++j) {
        int r = wn * 64 + j * 16 + (lane & 15);
        bg[j] = *(const short8*)&lds[8192 + r * 64 + ((ch ^ (r & 7)) << 3)];
      }
      #pragma unroll
      for (int i = 0; i < 4; ++i)
        #pragma unroll
        for (int j = 0; j < 4; ++j)
          acc[i][j] = __builtin_amdgcn_mfma_f32_16x16x32_bf16(af[i], bg[j], acc[i][j], 0, 0, 0);
    }
  }
  __syncthreads();            // LDS free for reuse

  int* lcount = (int*)lds;                           // 128 ints
  unsigned int* lcand = (unsigned int*)lds + 128;    // 128*SLOTS
  if (t < 128) lcount[t] = 0;
  __syncthreads();

  float e2c[4];
  #pragma unroll
  for (int j = 0; j < 4; ++j) e2c[j] = e2[bn * 128 + wn * 64 + j * 16 + (lane & 15)];

  #pragma unroll
  for (int i = 0; i < 4; ++i) {
    int rb = wm * 64 + i * 16 + (lane >> 4) * 4;
    float q2r[4], t2r[4];
    #pragma unroll
    for (int reg = 0; reg < 4; ++reg) {
      q2r[reg] = q2[bm * 128 + rb + reg];
      t2r[reg] = thr2[bm * 128 + rb + reg];
    }
    #pragma unroll
    for (int j = 0; j < 4; ++j) {
      int gcol = bn * 128 + wn * 64 + j * 16 + (lane & 15);
      #pragma unroll
      for (int reg = 0; reg < 4; ++reg) {
        float d2 = fmaf(-2.0f, acc[i][j][reg], q2r[reg]) + e2c[j];
        if (d2 <= t2r[reg]) {
          int lr = rb + reg;
          unsigned short hb = __half_as_ushort(__float2half(fmaxf(d2, 0.f)));
          int slot = atomicAdd(&lcount[lr], 1);
          if (slot < SLOTS)
            lcand[lr * SLOTS + slot] = ((unsigned int)hb << 16) | (unsigned int)gcol;
        }
      }
    }
  }
  __syncthreads();

  if (t < 128) {
    int n = lcount[t];
    int grow = bm * 128 + t;
    if (n > SLOTS) { flag[grow] = 1; n = SLOTS; }
    if (n > 0) {
      int base = atomicAdd(&ccount[grow], n);
      for (int k = 0; k < n; ++k) {
        int p = base + k;
        if (p < CAP) cand[(size_t)grow * CAP + p] = lcand[t * SLOTS + k];
      }
    }
  }
}

// ---- refine (per-wave) + inline brute-force fixup (per-block) ----
__global__ __launch_bounds__(256) void refine_fix(
    const unsigned int* __restrict__ cand, const int* __restrict__ ccount,
    const float* __restrict__ enc, const float* __restrict__ e2,
    const float* __restrict__ q2, const float* __restrict__ thr,
    const int* __restrict__ hard, const float* __restrict__ maxg,
    const int* __restrict__ idxs, const int* __restrict__ flag,
    float* __restrict__ out) {
  __shared__ char smem[35072];
  // refine overlay
  unsigned int* keys = (unsigned int*)smem;              // [4][CAP]   4 KB
  unsigned int* ambi = keys + 4 * CAP;                   // [4][64]    1 KB
  float* exd  = (float*)(ambi + 4 * 64);                 // [4][64]    1 KB
  int* chist  = (int*)(exd + 4 * 64);                    // [4][NC]
  int* acount = chist + 4 * NC;                          // [4]
  int* lflag  = acount + 4;                              // [4]
  // fixup overlay (reused after barrier)
  float* rowb = (float*)smem;                            // [NB] 32 KB
  float* qsh  = (float*)(smem + 32768);                  // [256]
  int*  hist  = (int*)(smem + 33792);                    // [256]
  float* wredf = (float*)(smem + 34816);                 // [4]
  int*  wredi  = (int*)(smem + 34832);                   // [4]
  int*  binfo  = (int*)(smem + 34848);                   // [2]
  int*  chist2 = (int*)(smem + 34856);                   // [NC]

  const int t = threadIdx.x, lane = t & 63, wv = t >> 6;
  const int s0 = blockIdx.x * 4;
  const int s = s0 + wv;
  const int qi = idxs[s];
  const float q2v = q2[s];
  const float tv = thr[s];
  const int cnt = ccount[s];

  if (lane == 0) { lflag[wv] = flag[s]; acount[wv] = 0; }
  if (lane < NC) chist[wv * NC + lane] = 0;

  bool bad = (flag[s] != 0) || (cnt < SEL) || (cnt > CAP);
  const int nc = bad ? 0 : cnt;

  if (!bad) {
    unsigned int* kw = keys + wv * CAP;
    for (int k = lane; k < nc; k += 64) kw[k] = cand[(size_t)s * CAP + k];

    // 26th-smallest key (distinct keys; f16>=0 so uint order = value order)
    unsigned int mykth = 0xFFFFFFFFu;
    for (int k = lane; k < nc; k += 64) {
      unsigned int ki = kw[k];
      int r = 0;
      for (int j = 0; j < nc; ++j) r += (kw[j] < ki) ? 1 : 0;
      if (r == SEL - 1) mykth = ki;
    }
    unsigned long long bal = __ballot(mykth != 0xFFFFFFFFu);
    int srcl = __ffsll((unsigned long long)bal) - 1;
    unsigned int kthkey = (unsigned int)__shfl((int)mykth, srcl, 64);
    float kv = h2f((unsigned short)(kthkey >> 16));

    if (kv > tv - 2.f * EPSA) {
      bad = true;
      if (lane == 0) lflag[wv] = 1;
    } else {
      const float lo = kv - 2.f * EPSA, hi = kv + 2.f * EPSA;
      int nbl = 0;
      for (int k = lane; k < nc; k += 64) {
        unsigned int ki = kw[k];
        float av = h2f((unsigned short)(ki >> 16));
        int col = (int)(ki & 0x1FFFu);
        if (av < lo) {
          ++nbl;
          atomicAdd(&chist[wv * NC + hard[col]], 1);
        } else if (av <= hi) {
          int sl = atomicAdd(&acount[wv], 1);
          if (sl < 64) ambi[wv * 64 + sl] = (unsigned int)col;
        }
      }
      #pragma unroll
      for (int o = 32; o; o >>= 1) nbl += __shfl_down(nbl, o, 64);
      int nbelow = __shfl(nbl, 0, 64);
      int na = acount[wv];
      if (na > 64) {
        bad = true;
        if (lane == 0) lflag[wv] = 1;
      } else {
        const int g = lane >> 4, sl = lane & 15;
        float4 qf[4];
        #pragma unroll
        for (int j = 0; j < 4; ++j)
          qf[j] = ((const float4*)(enc + (size_t)qi * NENC))[sl * 4 + j];
        for (int a0 = g; a0 < na; a0 += 4) {
          int col = (int)ambi[wv * 64 + a0];
          const float4* er = (const float4*)(enc + (size_t)col * NENC);
          float p = 0.f;
          #pragma unroll
          for (int j = 0; j < 4; ++j) {
            float4 ev = er[sl * 4 + j];
            p += qf[j].x * ev.x + qf[j].y * ev.y + qf[j].z * ev.z + qf[j].w * ev.w;
          }
          #pragma unroll
          for (int o2 = 1; o2 < 16; o2 <<= 1) p += __shfl_xor(p, o2, 64);
          if (sl == 0) exd[wv * 64 + a0] = sqrtf(fmaxf((q2v - 2.0f * p) + e2[col], 0.f));
        }

        int rank1 = SEL - nbelow;
        float myv = (lane < na) ? exd[wv * 64 + lane] : 1e30f;
        int rl = 0, re = 0;
        for (int j = 0; j < na; ++j) {
          float ov = exd[wv * 64 + j];
          rl += (ov < myv) ? 1 : 0;
          re += (ov == myv) ? 1 : 0;
        }
        float mykv = 1e30f;
        if (lane < na && rl <= rank1 - 1 && rank1 - 1 < rl + re) mykv = myv;
        #pragma unroll
        for (int o = 32; o; o >>= 1) mykv = fminf(mykv, __shfl_down(mykv, o, 64));
        float kthdd = __shfl(mykv, 0, 64);

        int nin = 0;
        for (int k = lane; k < na; k += 64) {
          if (exd[wv * 64 + k] < kthdd) {
            ++nin;
            atomicAdd(&chist[wv * NC + hard[(int)ambi[wv * 64 + k]]], 1);
          }
        }
        #pragma unroll
        for (int o = 32; o; o >>= 1) nin += __shfl_down(nin, o, 64);

        if (lane == 0) {
          float fn = (float)(nbelow + nin);
          float pur = 0.f;
          for (int c = 0; c < NC; ++c) {
            float p = (float)chist[wv * NC + c] / fn;
            pur -= p * logf(p + 1e-5f);
          }
          out[s] = pur * maxg[qi];
        }
      }
    }
  }

  // ---- phase 2: block-uniform brute-force for flagged rows (never expected) ----
  __syncthreads();
  int f0 = lflag[0], f1 = lflag[1], f2 = lflag[2], f3 = lflag[3];
  __syncthreads();   // all reads done before overlay reuse
  if (!(f0 | f1 | f2 | f3)) return;

  for (int r = 0; r < 4; ++r) {
    int fr = (r == 0) ? f0 : (r == 1) ? f1 : (r == 2) ? f2 : f3;
    if (!fr) continue;
    const int sf = s0 + r;
    const int qif = idxs[sf];
    qsh[t] = enc[(size_t)qif * NENC + t];
    hist[t] = 0;
    if (t < NC) chist2[t] = 0;
    __syncthreads();

    float4 q4 = ((const float4*)qsh)[lane];
    float q2f = e2[qif];
    for (int p = wv; p < NB; p += 4) {
      float4 ev = ((const float4*)(enc + (size_t)p * NENC))[lane];
      float pr = q4.x * ev.x + q4.y * ev.y + q4.z * ev.z + q4.w * ev.w;
      #pragma unroll
      for (int o = 32; o; o >>= 1) pr += __shfl_down(pr, o, 64);
      if (lane == 0) rowb[p] = sqrtf(fmaxf((q2f - 2.0f * pr) + e2[p], 0.f));
    }
    __syncthreads();

    float lmax = 0.f;
    for (int u = 0; u < 32; ++u) lmax = fmaxf(lmax, rowb[t + u * 256]);
    #pragma unroll
    for (int o = 32; o; o >>= 1) lmax = fmaxf(lmax, __shfl_down(lmax, o, 64));
    if (lane == 0) wredf[wv] = lmax;
    __syncthreads();
    float smax = fmaxf(fmaxf(wredf[0], wredf[1]), fmaxf(wredf[2], wredf[3]));
    float scale = smax > 0.f ? 256.f / smax : 0.f;

    for (int u = 0; u < 32; ++u) {
      float v = rowb[t + u * 256];
      int b = (int)(v * scale);
      b = b > 255 ? 255 : b;
      atomicAdd(&hist[b], 1);
    }
    __syncthreads();
    if (t == 0) {
      int cum = 0, j = 0;
      for (; j < 256; ++j) { cum += hist[j]; if (cum >= SEL) break; }
      if (j > 255) j = 255;
      binfo[0] = j;
      binfo[1] = SEL - (cum - hist[j]);
    }
    __syncthreads();
    const int jbin = binfo[0];
    int rank = binfo[1];

    float kth = 0.f, last = -1.f;
    bool first = true;
    for (int iter = 0; iter < 32; ++iter) {
      float lmin = INFINITY;
      for (int u = 0; u < 32; ++u) {
        float v = rowb[t + u * 256];
        bool elig;
        if (first) {
          int b = (int)(v * scale);
          b = b > 255 ? 255 : b;
          elig = (b >= jbin);
        } else {
          elig = (v > last);
        }
        if (elig) lmin = fminf(lmin, v);
      }
      #pragma unroll
      for (int o = 32; o; o >>= 1) lmin = fminf(lmin, __shfl_down(lmin, o, 64));
      __syncthreads();
      if (lane == 0) wredf[wv] = lmin;
      __syncthreads();
      float m = fminf(fminf(wredf[0], wredf[1]), fminf(wredf[2], wredf[3]));

      int lc = 0;
      for (int u = 0; u < 32; ++u) lc += (rowb[t + u * 256] == m) ? 1 : 0;
      #pragma unroll
      for (int o = 32; o; o >>= 1) lc += __shfl_down(lc, o, 64);
      __syncthreads();
      if (lane == 0) wredi[wv] = lc;
      __syncthreads();
      int c = wredi[0] + wredi[1] + wredi[2] + wredi[3];

      kth = m;
      if (c >= rank) break;
      rank -= c;
      last = m;
      first = false;
    }

    int ln = 0;
    for (int u = 0; u < 32; ++u) {
      int i = t + u * 256;
      if (rowb[i] < kth) { atomicAdd(&chist2[hard[i]], 1); ++ln; }
    }
    #pragma unroll
    for (int o = 32; o; o >>= 1) ln += __shfl_down(ln, o, 64);
    __syncthreads();
    if (lane == 0) wredi[wv] = ln;
    __syncthreads();
    if (t == 0) {
      float fn = (float)(wredi[0] + wredi[1] + wredi[2] + wredi[3]);
      float pur = 0.f;
      for (int c = 0; c < NC; ++c) {
        float p = (float)chist2[c] / fn;
        pur -= p * logf(p + 1e-5f);
      }
      out[sf] = pur * maxg[qif];
    }
    __syncthreads();
  }
}

// ---------------- launch ----------------
extern "C" void kernel_launch(void* const* d_in, const int* in_sizes, int n_in,
                              void* d_out, int out_size, void* d_ws, size_t ws_size,
                              hipStream_t stream) {
  const float* enc = (const float*)d_in[0];
  const float* cat = (const float*)d_in[1];
  const int* idxs = (const int*)d_in[2];
  float* out = (float*)d_out;

  char* ws = (char*)d_ws;
  float* e2    = (float*)ws;                  // NB
  float* maxg  = e2 + NB;                     // NB
  float* q2    = maxg + NB;                   // NS
  float* thr   = q2 + NS;                     // NS
  float* thr2  = thr + NS;                    // NS
  float* smoms = thr2 + NS;                   // 2
  int*   hard   = (int*)(smoms + 2);          // NB
  int*   ccount = hard + NB;                  // NS
  int*   flag   = ccount + NS;                // NS
  unsigned int* cand = (unsigned int*)(flag + NS);       // NS*CAP
  ushort* Abf = (ushort*)(cand + (size_t)NS * CAP);      // NS*NENC
  ushort* Bbf = Abf + (size_t)NS * NENC;                 // NB*NENC

  hipMemsetAsync(smoms, 0, 2 * sizeof(float), stream);
  prep_kernel<<<dim3(NB / 4), dim3(256), 0, stream>>>(enc, cat, e2, maxg, hard, Bbf,
                                                      smoms, ccount, flag);
  thr_kernel<<<dim3(NS / 4), dim3(256), 0, stream>>>(enc, idxs, e2, smoms, Abf,
                                                     q2, thr, thr2);
  d2gemm<<<dim3(4096), dim3(256), 0, stream>>>(Abf, Bbf, q2, e2, thr2, ccount, cand, flag);
  refine_fix<<<dim3(NS / 4), dim3(256), 0, stream>>>(cand, ccount, enc, e2, q2, thr,
                                                     hard, maxg, idxs, flag, out);
}

// Round 12
// 210.776 us; speedup vs baseline: 1.4234x; 1.4234x over previous
//
#include <hip/hip_runtime.h>
#include <hip/hip_fp16.h>
#include <hip/hip_bf16.h>
#include <math.h>

#define NB   8192
#define NENC 256
#define NC   25
#define NS   8192
#define SEL  26      // K+1
#define CAP  256
#define EPSA 1.25f   // |approx(f16) - true| d2 bound
#define ZSIG 2.2f
#define SLOTS 16     // per-(row,128-col-block) budget

typedef __attribute__((ext_vector_type(8))) short short8;
typedef __attribute__((ext_vector_type(4))) float f32x4;

__device__ __forceinline__ void gload_lds16(const void* g, void* l) {
  __builtin_amdgcn_global_load_lds(
      (const __attribute__((address_space(1))) unsigned int*)g,
      (__attribute__((address_space(3))) unsigned int*)l,
      16, 0, 0);
}
__device__ __forceinline__ float h2f(unsigned short u) {
  return __half2float(__ushort_as_half(u));
}

// ---- prep: e2, argmax, confidence, bf16 B, e2-moment atomics, zero ccount/flag ----
__global__ __launch_bounds__(256) void prep_kernel(
    const float* __restrict__ enc, const float* __restrict__ cat,
    float* __restrict__ e2, float* __restrict__ maxg, int* __restrict__ hard,
    ushort* __restrict__ Bbf, float* __restrict__ smoms,
    int* __restrict__ ccount, int* __restrict__ flag) {
  __shared__ float pr[8];
  int gt = blockIdx.x * 256 + threadIdx.x;
  int w = gt >> 6;
  int lane = gt & 63;

  if (gt < NS) { ccount[gt] = 0; flag[gt] = 0; }   // consumed by later dispatches

  float4 v = ((const float4*)(enc + (size_t)w * NENC))[lane];
  ushort4 o;
  __hip_bfloat16 h;
  h = __float2bfloat16(v.x); o.x = *(unsigned short*)&h;
  h = __float2bfloat16(v.y); o.y = *(unsigned short*)&h;
  h = __float2bfloat16(v.z); o.z = *(unsigned short*)&h;
  h = __float2bfloat16(v.w); o.w = *(unsigned short*)&h;
  ((ushort4*)(Bbf + (size_t)w * NENC))[lane] = o;

  float ss = v.x * v.x + v.y * v.y + v.z * v.z + v.w * v.w;
  #pragma unroll
  for (int ofs = 32; ofs; ofs >>= 1) ss += __shfl_down(ss, ofs, 64);

  float mv = -INFINITY;
  int mi = 0;
  if (lane < NC) { mv = cat[(size_t)w * NC + lane]; mi = lane; }
  #pragma unroll
  for (int ofs = 32; ofs; ofs >>= 1) {
    float ov = __shfl_down(mv, ofs, 64);
    int   oi = __shfl_down(mi, ofs, 64);
    if (ov > mv || (ov == mv && oi < mi)) { mv = ov; mi = oi; }
  }
  int wv = threadIdx.x >> 6;
  if (lane == 0) {
    e2[w] = ss; maxg[w] = mv; hard[w] = mi;
    pr[wv] = ss; pr[4 + wv] = ss * ss;
  }
  __syncthreads();
  if (threadIdx.x == 0) {
    atomicAdd(&smoms[0], pr[0] + pr[1] + pr[2] + pr[3]);
    atomicAdd(&smoms[1], pr[4] + pr[5] + pr[6] + pr[7]);
  }
}

// ---- thr: gather A (bf16), q2, per-row thresholds (pure fn of e2[qi] + moments) ----
__global__ __launch_bounds__(256) void thr_kernel(
    const float* __restrict__ enc, const int* __restrict__ idxs,
    const float* __restrict__ e2, const float* __restrict__ smoms,
    ushort* __restrict__ Abf, float* __restrict__ q2,
    float* __restrict__ thr, float* __restrict__ thr2) {
  int gt = blockIdx.x * 256 + threadIdx.x;
  int s = gt >> 6, lane = gt & 63;
  int qi = idxs[s];
  float4 v = ((const float4*)(enc + (size_t)qi * NENC))[lane];
  ushort4 o;
  __hip_bfloat16 h;
  h = __float2bfloat16(v.x); o.x = *(unsigned short*)&h;
  h = __float2bfloat16(v.y); o.y = *(unsigned short*)&h;
  h = __float2bfloat16(v.z); o.z = *(unsigned short*)&h;
  h = __float2bfloat16(v.w); o.w = *(unsigned short*)&h;
  ((ushort4*)(Abf + (size_t)s * NENC))[lane] = o;

  if (lane == 0) {
    float q2v = e2[qi];
    float me2 = smoms[0] * (1.f / NB);
    float ve2 = smoms[1] * (1.f / NB) - me2 * me2;
    float mu  = q2v + me2;                 // qm term dropped: |2qm| <~ 1.5 << guard gap
    float sig = sqrtf(fmaxf(ve2 + 4.2f * q2v * (me2 / (float)NENC), 1e-3f));
    float tv  = mu - ZSIG * sig;
    q2[s]  = q2v;
    thr[s] = tv;
    if (tv > 0.f) {
      __half hf = __float2half_rd(tv);
      unsigned short hb = __half_as_ushort(hf);
      float mid = 0.5f * (__half2float(hf) + h2f((unsigned short)(hb + 1)));
      thr2[s] = mid;
    } else {
      thr2[s] = tv;
    }
  }
}

// ---- 128x128 bf16 MFMA GEMM (4 blk/CU — proven no-spill) + candidate collect ----
__global__ __launch_bounds__(256, 4) void d2gemm(
    const ushort* __restrict__ Abf, const ushort* __restrict__ Bbf,
    const float* __restrict__ q2, const float* __restrict__ e2,
    const float* __restrict__ thr2, int* __restrict__ ccount,
    unsigned int* __restrict__ cand, int* __restrict__ flag) {
  __shared__ ushort lds[16384];   // A [0,8192) + B [8192,16384) : 32 KB

  const int t = threadIdx.x, lane = t & 63, w = t >> 6;
  int id = blockIdx.x;
  int wg = (id & 7) * 512 + (id >> 3);     // bijective XCD remap, nwg = 4096 = 8*512
  const int bm = wg >> 6, bn = wg & 63;
  const int wm = w >> 1, wn = w & 1;

  f32x4 acc[4][4];
  #pragma unroll
  for (int i = 0; i < 4; ++i)
    #pragma unroll
    for (int j = 0; j < 4; ++j) acc[i][j] = (f32x4){0.f, 0.f, 0.f, 0.f};

  const ushort* Ab = Abf + (size_t)(bm * 128) * NENC;
  const ushort* Bb = Bbf + (size_t)(bn * 128) * NENC;

  for (int kk = 0; kk < NENC; kk += 64) {
    if (kk) __syncthreads();
    #pragma unroll
    for (int u = 0; u < 4; ++u) {
      int flat = u * 256 + t;
      int r = flat >> 3, c = flat & 7;
      gload_lds16(Ab + (size_t)r * NENC + kk + ((c ^ (r & 7)) << 3),
                  (char*)lds + (u * 4 + w) * 1024);
    }
    #pragma unroll
    for (int u = 0; u < 4; ++u) {
      int flat = u * 256 + t;
      int r = flat >> 3, c = flat & 7;
      gload_lds16(Bb + (size_t)r * NENC + kk + ((c ^ (r & 7)) << 3),
                  (char*)lds + 16384 + (u * 4 + w) * 1024);
    }
    __syncthreads();

    #pragma unroll
    for (int kf = 0; kf < 2; ++kf) {
      short8 af[4], bg[4];
      int ch = kf * 4 + (lane >> 4);
      #pragma unroll
      for (int i = 0; i < 4; ++i) {
        int r = wm * 64 + i * 16 + (lane & 15);
        af[i] = *(const short8*)&lds[r * 64 + ((ch ^ (r & 7)) << 3)];
      }
      #pragma unroll
      for (int j = 0; j < 4; ++j) {
        int r = wn * 64 + j * 16 + (lane & 15);
        bg[j] = *(const short8*)&lds[8192 + r * 64 + ((ch ^ (r & 7)) << 3)];
      }
      #pragma unroll
      for (int i = 0; i < 4; ++i)
        #pragma unroll
        for (int j = 0; j < 4; ++j)
          acc[i][j] = __builtin_amdgcn_mfma_f32_16x16x32_bf16(af[i], bg[j], acc[i][j], 0, 0, 0);
    }
  }
  __syncthreads();            // LDS free for reuse

  int* lcount = (int*)lds;                           // 128 ints
  unsigned int* lcand = (unsigned int*)lds + 128;    // 128*SLOTS
  if (t < 128) lcount[t] = 0;
  __syncthreads();

  float e2c[4];
  #pragma unroll
  for (int j = 0; j < 4; ++j) e2c[j] = e2[bn * 128 + wn * 64 + j * 16 + (lane & 15)];

  #pragma unroll
  for (int i = 0; i < 4; ++i) {
    int rb = wm * 64 + i * 16 + (lane >> 4) * 4;
    float q2r[4], t2r[4];
    #pragma unroll
    for (int reg = 0; reg < 4; ++reg) {
      q2r[reg] = q2[bm * 128 + rb + reg];
      t2r[reg] = thr2[bm * 128 + rb + reg];
    }
    #pragma unroll
    for (int j = 0; j < 4; ++j) {
      int gcol = bn * 128 + wn * 64 + j * 16 + (lane & 15);
      #pragma unroll
      for (int reg = 0; reg < 4; ++reg) {
        float d2 = fmaf(-2.0f, acc[i][j][reg], q2r[reg]) + e2c[j];
        if (d2 <= t2r[reg]) {
          int lr = rb + reg;
          unsigned short hb = __half_as_ushort(__float2half(fmaxf(d2, 0.f)));
          int slot = atomicAdd(&lcount[lr], 1);
          if (slot < SLOTS)
            lcand[lr * SLOTS + slot] = ((unsigned int)hb << 16) | (unsigned int)gcol;
        }
      }
    }
  }
  __syncthreads();

  if (t < 128) {
    int n = lcount[t];
    int grow = bm * 128 + t;
    if (n > SLOTS) { flag[grow] = 1; n = SLOTS; }
    if (n > 0) {
      int base = atomicAdd(&ccount[grow], n);
      for (int k = 0; k < n; ++k) {
        int p = base + k;
        if (p < CAP) cand[(size_t)grow * CAP + p] = lcand[t * SLOTS + k];
      }
    }
  }
}

// ---- refine: kth among candidates, exact band, entropy (small smem, per-wave) ----
__global__ __launch_bounds__(256) void refine_kernel(
    const unsigned int* __restrict__ cand, const int* __restrict__ ccount,
    const float* __restrict__ enc, const float* __restrict__ e2,
    const float* __restrict__ q2, const float* __restrict__ thr,
    const int* __restrict__ hard, const float* __restrict__ maxg,
    const int* __restrict__ idxs, int* __restrict__ flag,
    float* __restrict__ out) {
  __shared__ unsigned int keys[4][CAP];
  __shared__ unsigned int ambi[4][64];
  __shared__ float exd[4][64];
  __shared__ int chist[4][NC];
  __shared__ int acount[4];

  const int t = threadIdx.x, lane = t & 63, wv = t >> 6;
  const int s = blockIdx.x * 4 + wv;
  const int qi = idxs[s];
  const float q2v = q2[s];
  const float tv = thr[s];
  const int cnt = ccount[s];

  if (flag[s] || cnt < SEL || cnt > CAP) {
    if (lane == 0) flag[s] = 1;
    return;
  }
  const int nc = cnt;

  for (int k = lane; k < nc; k += 64) keys[wv][k] = cand[(size_t)s * CAP + k];
  if (lane == 0) acount[wv] = 0;
  if (lane < NC) chist[wv][lane] = 0;

  unsigned int mykth = 0xFFFFFFFFu;
  for (int k = lane; k < nc; k += 64) {
    unsigned int ki = keys[wv][k];
    int r = 0;
    for (int j = 0; j < nc; ++j) r += (keys[wv][j] < ki) ? 1 : 0;
    if (r == SEL - 1) mykth = ki;
  }
  unsigned long long bal = __ballot(mykth != 0xFFFFFFFFu);
  int srcl = __ffsll((unsigned long long)bal) - 1;
  unsigned int kthkey = (unsigned int)__shfl((int)mykth, srcl, 64);
  float kv = h2f((unsigned short)(kthkey >> 16));

  if (kv > tv - 2.f * EPSA) {
    if (lane == 0) flag[s] = 1;
    return;
  }
  const float lo = kv - 2.f * EPSA, hi = kv + 2.f * EPSA;

  int nbl = 0;
  for (int k = lane; k < nc; k += 64) {
    unsigned int ki = keys[wv][k];
    float av = h2f((unsigned short)(ki >> 16));
    int col = (int)(ki & 0x1FFFu);
    if (av < lo) {
      ++nbl;
      atomicAdd(&chist[wv][hard[col]], 1);
    } else if (av <= hi) {
      int sl = atomicAdd(&acount[wv], 1);
      if (sl < 64) ambi[wv][sl] = (unsigned int)col;
    }
  }
  #pragma unroll
  for (int o = 32; o; o >>= 1) nbl += __shfl_down(nbl, o, 64);
  int nbelow = __shfl(nbl, 0, 64);
  int na = acount[wv];
  if (na > 64) {
    if (lane == 0) flag[s] = 1;
    return;
  }

  const int g = lane >> 4, sl = lane & 15;
  float4 qf[4];
  #pragma unroll
  for (int j = 0; j < 4; ++j) qf[j] = ((const float4*)(enc + (size_t)qi * NENC))[sl * 4 + j];
  for (int a0 = g; a0 < na; a0 += 4) {
    int col = (int)ambi[wv][a0];
    const float4* er = (const float4*)(enc + (size_t)col * NENC);
    float p = 0.f;
    #pragma unroll
    for (int j = 0; j < 4; ++j) {
      float4 ev = er[sl * 4 + j];
      p += qf[j].x * ev.x + qf[j].y * ev.y + qf[j].z * ev.z + qf[j].w * ev.w;
    }
    #pragma unroll
    for (int o2 = 1; o2 < 16; o2 <<= 1) p += __shfl_xor(p, o2, 64);
    if (sl == 0) exd[wv][a0] = sqrtf(fmaxf((q2v - 2.0f * p) + e2[col], 0.f));
  }

  int rank1 = SEL - nbelow;
  float myv = (lane < na) ? exd[wv][lane] : 1e30f;
  int rl = 0, re = 0;
  for (int j = 0; j < na; ++j) {
    float ov = exd[wv][j];
    rl += (ov < myv) ? 1 : 0;
    re += (ov == myv) ? 1 : 0;
  }
  float mykv = 1e30f;
  if (lane < na && rl <= rank1 - 1 && rank1 - 1 < rl + re) mykv = myv;
  #pragma unroll
  for (int o = 32; o; o >>= 1) mykv = fminf(mykv, __shfl_down(mykv, o, 64));
  float kthdd = __shfl(mykv, 0, 64);

  int nin = 0;
  for (int k = lane; k < na; k += 64) {
    if (exd[wv][k] < kthdd) {
      ++nin;
      atomicAdd(&chist[wv][hard[(int)ambi[wv][k]]], 1);
    }
  }
  #pragma unroll
  for (int o = 32; o; o >>= 1) nin += __shfl_down(nin, o, 64);

  if (lane == 0) {
    float fn = (float)(nbelow + nin);
    float pur = 0.f;
    for (int c = 0; c < NC; ++c) {
      float p = (float)chist[wv][c] / fn;
      pur -= p * logf(p + 1e-5f);
    }
    out[s] = pur * maxg[qi];
  }
}

// ---- fixup: exact brute force for flagged rows (never expected; early-exit) ----
__global__ __launch_bounds__(256) void fixup_kernel(
    const float* __restrict__ enc, const float* __restrict__ e2,
    const int* __restrict__ hard, const float* __restrict__ maxg,
    const int* __restrict__ idxs, const int* __restrict__ flag,
    float* __restrict__ out) {
  const int s = blockIdx.x;
  if (!flag[s]) return;

  __shared__ float row[NB];
  __shared__ float qsh[NENC];
  __shared__ int   hist[256];
  __shared__ float wredf[4];
  __shared__ int   wredi[4];
  __shared__ int   binfo[2];
  __shared__ int   chist2[NC];

  const int t = threadIdx.x, lane = t & 63, wv = t >> 6;
  const int qi = idxs[s];
  qsh[t] = enc[(size_t)qi * NENC + t];
  hist[t] = 0;
  if (t < NC) chist2[t] = 0;
  __syncthreads();

  float4 q4 = ((const float4*)qsh)[lane];
  float q2v = e2[qi];
  for (int p = wv; p < NB; p += 4) {
    float4 ev = ((const float4*)(enc + (size_t)p * NENC))[lane];
    float pr = q4.x * ev.x + q4.y * ev.y + q4.z * ev.z + q4.w * ev.w;
    #pragma unroll
    for (int o = 32; o; o >>= 1) pr += __shfl_down(pr, o, 64);
    if (lane == 0) row[p] = sqrtf(fmaxf((q2v - 2.0f * pr) + e2[p], 0.f));
  }
  __syncthreads();

  float lmax = 0.f;
  for (int u = 0; u < 32; ++u) lmax = fmaxf(lmax, row[t + u * 256]);
  #pragma unroll
  for (int o = 32; o; o >>= 1) lmax = fmaxf(lmax, __shfl_down(lmax, o, 64));
  if (lane == 0) wredf[wv] = lmax;
  __syncthreads();
  float smax = fmaxf(fmaxf(wredf[0], wredf[1]), fmaxf(wredf[2], wredf[3]));
  float scale = smax > 0.f ? 256.f / smax : 0.f;

  for (int u = 0; u < 32; ++u) {
    float v = row[t + u * 256];
    int b = (int)(v * scale);
    b = b > 255 ? 255 : b;
    atomicAdd(&hist[b], 1);
  }
  __syncthreads();
  if (t == 0) {
    int cum = 0, j = 0;
    for (; j < 256; ++j) { cum += hist[j]; if (cum >= SEL) break; }
    if (j > 255) j = 255;
    binfo[0] = j;
    binfo[1] = SEL - (cum - hist[j]);
  }
  __syncthreads();
  const int jbin = binfo[0];
  int rank = binfo[1];

  float kth = 0.f, last = -1.f;
  bool first = true;
  for (int iter = 0; iter < 32; ++iter) {
    float lmin = INFINITY;
    for (int u = 0; u < 32; ++u) {
      float v = row[t + u * 256];
      bool elig;
      if (first) {
        int b = (int)(v * scale);
        b = b > 255 ? 255 : b;
        elig = (b >= jbin);
      } else {
        elig = (v > last);
      }
      if (elig) lmin = fminf(lmin, v);
    }
    #pragma unroll
    for (int o = 32; o; o >>= 1) lmin = fminf(lmin, __shfl_down(lmin, o, 64));
    __syncthreads();
    if (lane == 0) wredf[wv] = lmin;
    __syncthreads();
    float m = fminf(fminf(wredf[0], wredf[1]), fminf(wredf[2], wredf[3]));

    int lc = 0;
    for (int u = 0; u < 32; ++u) lc += (row[t + u * 256] == m) ? 1 : 0;
    #pragma unroll
    for (int o = 32; o; o >>= 1) lc += __shfl_down(lc, o, 64);
    __syncthreads();
    if (lane == 0) wredi[wv] = lc;
    __syncthreads();
    int c = wredi[0] + wredi[1] + wredi[2] + wredi[3];

    kth = m;
    if (c >= rank) break;
    rank -= c;
    last = m;
    first = false;
  }

  int ln = 0;
  for (int u = 0; u < 32; ++u) {
    int i = t + u * 256;
    if (row[i] < kth) { atomicAdd(&chist2[hard[i]], 1); ++ln; }
  }
  #pragma unroll
  for (int o = 32; o; o >>= 1) ln += __shfl_down(ln, o, 64);
  __syncthreads();
  if (lane == 0) wredi[wv] = ln;
  __syncthreads();
  if (t == 0) {
    float fn = (float)(wredi[0] + wredi[1] + wredi[2] + wredi[3]);
    float pur = 0.f;
    for (int c = 0; c < NC; ++c) {
      float p = (float)chist2[c] / fn;
      pur -= p * logf(p + 1e-5f);
    }
    out[s] = pur * maxg[qi];
  }
}

// ---------------- launch ----------------
extern "C" void kernel_launch(void* const* d_in, const int* in_sizes, int n_in,
                              void* d_out, int out_size, void* d_ws, size_t ws_size,
                              hipStream_t stream) {
  const float* enc = (const float*)d_in[0];
  const float* cat = (const float*)d_in[1];
  const int* idxs = (const int*)d_in[2];
  float* out = (float*)d_out;

  char* ws = (char*)d_ws;
  float* e2    = (float*)ws;                  // NB
  float* maxg  = e2 + NB;                     // NB
  float* q2    = maxg + NB;                   // NS
  float* thr   = q2 + NS;                     // NS
  float* thr2  = thr + NS;                    // NS
  float* smoms = thr2 + NS;                   // 2
  int*   hard   = (int*)(smoms + 2);          // NB
  int*   ccount = hard + NB;                  // NS
  int*   flag   = ccount + NS;                // NS
  unsigned int* cand = (unsigned int*)(flag + NS);       // NS*CAP
  ushort* Abf = (ushort*)(cand + (size_t)NS * CAP);      // NS*NENC
  ushort* Bbf = Abf + (size_t)NS * NENC;                 // NB*NENC

  hipMemsetAsync(smoms, 0, 2 * sizeof(float), stream);
  prep_kernel<<<dim3(NB / 4), dim3(256), 0, stream>>>(enc, cat, e2, maxg, hard, Bbf,
                                                      smoms, ccount, flag);
  thr_kernel<<<dim3(NS / 4), dim3(256), 0, stream>>>(enc, idxs, e2, smoms, Abf,
                                                     q2, thr, thr2);
  d2gemm<<<dim3(4096), dim3(256), 0, stream>>>(Abf, Bbf, q2, e2, thr2, ccount, cand, flag);
  refine_kernel<<<dim3(NS / 4), dim3(256), 0, stream>>>(cand, ccount, enc, e2, q2, thr,
                                                        hard, maxg, idxs, flag, out);
  fixup_kernel<<<dim3(NS), dim3(256), 0, stream>>>(enc, e2, hard, maxg, idxs, flag, out);
}

// Round 14
// 158.134 us; speedup vs baseline: 1.8972x; 1.3329x over previous
//
#include <hip/hip_runtime.h>
#include <hip/hip_fp16.h>
#include <hip/hip_bf16.h>
#include <math.h>

#define NB   8192
#define NENC 256
#define NC   25
#define NS   8192
#define SEL  26      // K+1
#define CAP  256
#define EPSA 1.25f   // |approx(f16) - true| d2 bound
#define ZSIG 2.2f
#define SLOTS 16     // per-(row,128-col-block) budget
#define NPB  2048    // prep blocks (psum partials)

typedef __attribute__((ext_vector_type(8))) short short8;
typedef __attribute__((ext_vector_type(4))) float f32x4;

__device__ __forceinline__ void gload_lds16(const void* g, void* l) {
  __builtin_amdgcn_global_load_lds(
      (const __attribute__((address_space(1))) unsigned int*)g,
      (__attribute__((address_space(3))) unsigned int*)l,
      16, 0, 0);
}
__device__ __forceinline__ float h2f(unsigned short u) {
  return __half2float(__ushort_as_half(u));
}

// ---- prep: e2, argmax, confidence, bf16 B, per-block e2-moment partials ----
__global__ __launch_bounds__(256) void prep_kernel(
    const float* __restrict__ enc, const float* __restrict__ cat,
    float* __restrict__ e2, float* __restrict__ maxg, int* __restrict__ hard,
    ushort* __restrict__ Bbf, float* __restrict__ psum,
    int* __restrict__ ccount, int* __restrict__ flag) {
  __shared__ float pr[8];
  int gt = blockIdx.x * 256 + threadIdx.x;
  int w = gt >> 6;
  int lane = gt & 63;

  if (gt < NS) { ccount[gt] = 0; flag[gt] = 0; }   // consumed by later dispatches

  float4 v = ((const float4*)(enc + (size_t)w * NENC))[lane];
  ushort4 o;
  __hip_bfloat16 h;
  h = __float2bfloat16(v.x); o.x = *(unsigned short*)&h;
  h = __float2bfloat16(v.y); o.y = *(unsigned short*)&h;
  h = __float2bfloat16(v.z); o.z = *(unsigned short*)&h;
  h = __float2bfloat16(v.w); o.w = *(unsigned short*)&h;
  ((ushort4*)(Bbf + (size_t)w * NENC))[lane] = o;

  float ss = v.x * v.x + v.y * v.y + v.z * v.z + v.w * v.w;
  #pragma unroll
  for (int ofs = 32; ofs; ofs >>= 1) ss += __shfl_down(ss, ofs, 64);

  float mv = -INFINITY;
  int mi = 0;
  if (lane < NC) { mv = cat[(size_t)w * NC + lane]; mi = lane; }
  #pragma unroll
  for (int ofs = 32; ofs; ofs >>= 1) {
    float ov = __shfl_down(mv, ofs, 64);
    int   oi = __shfl_down(mi, ofs, 64);
    if (ov > mv || (ov == mv && oi < mi)) { mv = ov; mi = oi; }
  }
  int wv = threadIdx.x >> 6;
  if (lane == 0) {
    e2[w] = ss; maxg[w] = mv; hard[w] = mi;
    pr[wv] = ss; pr[4 + wv] = ss * ss;
  }
  __syncthreads();
  if (threadIdx.x == 0) {
    psum[blockIdx.x * 2]     = pr[0] + pr[1] + pr[2] + pr[3];   // plain stores, no init
    psum[blockIdx.x * 2 + 1] = pr[4] + pr[5] + pr[6] + pr[7];
  }
}

// ---- thr: reduce psum -> moments; gather A (bf16), q2, per-row thresholds ----
__global__ __launch_bounds__(256) void thr_kernel(
    const float* __restrict__ enc, const int* __restrict__ idxs,
    const float* __restrict__ e2, const float* __restrict__ psum,
    ushort* __restrict__ Abf, float* __restrict__ q2,
    float* __restrict__ thr, float* __restrict__ thr2) {
  __shared__ float red[16];
  // block-redundant moment reduction (psum is 16 KB, L2-resident)
  float s0 = 0.f, s1 = 0.f;
  for (int i = threadIdx.x; i < NPB; i += 256) {
    s0 += psum[2 * i];
    s1 += psum[2 * i + 1];
  }
  #pragma unroll
  for (int ofs = 32; ofs; ofs >>= 1) { s0 += __shfl_down(s0, ofs, 64); s1 += __shfl_down(s1, ofs, 64); }
  int wvi = threadIdx.x >> 6, ln = threadIdx.x & 63;
  if (ln == 0) { red[wvi] = s0; red[8 + wvi] = s1; }
  __syncthreads();
  float S0 = red[0] + red[1] + red[2] + red[3];
  float S1 = red[8] + red[9] + red[10] + red[11];

  int gt = blockIdx.x * 256 + threadIdx.x;
  int s = gt >> 6, lane = gt & 63;
  int qi = idxs[s];
  float4 v = ((const float4*)(enc + (size_t)qi * NENC))[lane];
  ushort4 o;
  __hip_bfloat16 h;
  h = __float2bfloat16(v.x); o.x = *(unsigned short*)&h;
  h = __float2bfloat16(v.y); o.y = *(unsigned short*)&h;
  h = __float2bfloat16(v.z); o.z = *(unsigned short*)&h;
  h = __float2bfloat16(v.w); o.w = *(unsigned short*)&h;
  ((ushort4*)(Abf + (size_t)s * NENC))[lane] = o;

  if (lane == 0) {
    float q2v = e2[qi];
    float me2 = S0 * (1.f / NB);
    float ve2 = S1 * (1.f / NB) - me2 * me2;
    float mu  = q2v + me2;                 // qm term dropped: |2qm| <~ 1.5 << guard gap
    float sig = sqrtf(fmaxf(ve2 + 4.2f * q2v * (me2 / (float)NENC), 1e-3f));
    float tv  = mu - ZSIG * sig;
    q2[s]  = q2v;
    thr[s] = tv;
    if (tv > 0.f) {
      __half hf = __float2half_rd(tv);
      unsigned short hb = __half_as_ushort(hf);
      float mid = 0.5f * (__half2float(hf) + h2f((unsigned short)(hb + 1)));
      thr2[s] = mid;
    } else {
      thr2[s] = tv;
    }
  }
}

// ---- 128x128 bf16 MFMA GEMM (4 blk/CU — proven no-spill) + candidate collect ----
__global__ __launch_bounds__(256, 4) void d2gemm(
    const ushort* __restrict__ Abf, const ushort* __restrict__ Bbf,
    const float* __restrict__ q2, const float* __restrict__ e2,
    const float* __restrict__ thr2, int* __restrict__ ccount,
    unsigned int* __restrict__ cand, int* __restrict__ flag) {
  __shared__ ushort lds[16384];   // A [0,8192) + B [8192,16384) : 32 KB

  const int t = threadIdx.x, lane = t & 63, w = t >> 6;
  int id = blockIdx.x;
  int wg = (id & 7) * 512 + (id >> 3);     // bijective XCD remap, nwg = 4096 = 8*512
  const int bm = wg >> 6, bn = wg & 63;
  const int wm = w >> 1, wn = w & 1;

  f32x4 acc[4][4];
  #pragma unroll
  for (int i = 0; i < 4; ++i)
    #pragma unroll
    for (int j = 0; j < 4; ++j) acc[i][j] = (f32x4){0.f, 0.f, 0.f, 0.f};

  const ushort* Ab = Abf + (size_t)(bm * 128) * NENC;
  const ushort* Bb = Bbf + (size_t)(bn * 128) * NENC;

  for (int kk = 0; kk < NENC; kk += 64) {
    if (kk) __syncthreads();
    #pragma unroll
    for (int u = 0; u < 4; ++u) {
      int flat = u * 256 + t;
      int r = flat >> 3, c = flat & 7;
      gload_lds16(Ab + (size_t)r * NENC + kk + ((c ^ (r & 7)) << 3),
                  (char*)lds + (u * 4 + w) * 1024);
    }
    #pragma unroll
    for (int u = 0; u < 4; ++u) {
      int flat = u * 256 + t;
      int r = flat >> 3, c = flat & 7;
      gload_lds16(Bb + (size_t)r * NENC + kk + ((c ^ (r & 7)) << 3),
                  (char*)lds + 16384 + (u * 4 + w) * 1024);
    }
    __syncthreads();

    #pragma unroll
    for (int kf = 0; kf < 2; ++kf) {
      short8 af[4], bg[4];
      int ch = kf * 4 + (lane >> 4);
      #pragma unroll
      for (int i = 0; i < 4; ++i) {
        int r = wm * 64 + i * 16 + (lane & 15);
        af[i] = *(const short8*)&lds[r * 64 + ((ch ^ (r & 7)) << 3)];
      }
      #pragma unroll
      for (int j = 0; j < 4; ++j) {
        int r = wn * 64 + j * 16 + (lane & 15);
        bg[j] = *(const short8*)&lds[8192 + r * 64 + ((ch ^ (r & 7)) << 3)];
      }
      #pragma unroll
      for (int i = 0; i < 4; ++i)
        #pragma unroll
        for (int j = 0; j < 4; ++j)
          acc[i][j] = __builtin_amdgcn_mfma_f32_16x16x32_bf16(af[i], bg[j], acc[i][j], 0, 0, 0);
    }
  }
  __syncthreads();            // LDS free for reuse

  int* lcount = (int*)lds;                           // 128 ints
  unsigned int* lcand = (unsigned int*)lds + 128;    // 128*SLOTS
  if (t < 128) lcount[t] = 0;
  __syncthreads();

  float e2c[4];
  #pragma unroll
  for (int j = 0; j < 4; ++j) e2c[j] = e2[bn * 128 + wn * 64 + j * 16 + (lane & 15)];

  #pragma unroll
  for (int i = 0; i < 4; ++i) {
    int rb = wm * 64 + i * 16 + (lane >> 4) * 4;
    float q2r[4], t2r[4];
    #pragma unroll
    for (int reg = 0; reg < 4; ++reg) {
      q2r[reg] = q2[bm * 128 + rb + reg];
      t2r[reg] = thr2[bm * 128 + rb + reg];
    }
    #pragma unroll
    for (int j = 0; j < 4; ++j) {
      int gcol = bn * 128 + wn * 64 + j * 16 + (lane & 15);
      #pragma unroll
      for (int reg = 0; reg < 4; ++reg) {
        float d2 = fmaf(-2.0f, acc[i][j][reg], q2r[reg]) + e2c[j];
        if (d2 <= t2r[reg]) {
          int lr = rb + reg;
          unsigned short hb = __half_as_ushort(__float2half(fmaxf(d2, 0.f)));
          int slot = atomicAdd(&lcount[lr], 1);
          if (slot < SLOTS)
            lcand[lr * SLOTS + slot] = ((unsigned int)hb << 16) | (unsigned int)gcol;
        }
      }
    }
  }
  __syncthreads();

  if (t < 128) {
    int n = lcount[t];
    int grow = bm * 128 + t;
    if (n > SLOTS) { flag[grow] = 1; n = SLOTS; }
    if (n > 0) {
      int base = atomicAdd(&ccount[grow], n);
      for (int k = 0; k < n; ++k) {
        int p = base + k;
        if (p < CAP) cand[(size_t)grow * CAP + p] = lcand[t * SLOTS + k];
      }
    }
  }
}

// ---- refine (per-wave) + inline brute-force fixup (per-block; verified R11) ----
__global__ __launch_bounds__(256) void refine_fix(
    const unsigned int* __restrict__ cand, const int* __restrict__ ccount,
    const float* __restrict__ enc, const float* __restrict__ e2,
    const float* __restrict__ q2, const float* __restrict__ thr,
    const int* __restrict__ hard, const float* __restrict__ maxg,
    const int* __restrict__ idxs, const int* __restrict__ flag,
    float* __restrict__ out) {
  __shared__ char smem[35072];
  // refine overlay
  unsigned int* keys = (unsigned int*)smem;              // [4][CAP]   4 KB
  unsigned int* ambi = keys + 4 * CAP;                   // [4][64]    1 KB
  float* exd  = (float*)(ambi + 4 * 64);                 // [4][64]    1 KB
  int* chist  = (int*)(exd + 4 * 64);                    // [4][NC]
  int* acount = chist + 4 * NC;                          // [4]
  int* lflag  = acount + 4;                              // [4]
  // fixup overlay (reused after barrier)
  float* rowb = (float*)smem;                            // [NB] 32 KB
  float* qsh  = (float*)(smem + 32768);                  // [256]
  int*  hist  = (int*)(smem + 33792);                    // [256]
  float* wredf = (float*)(smem + 34816);                 // [4]
  int*  wredi  = (int*)(smem + 34832);                   // [4]
  int*  binfo  = (int*)(smem + 34848);                   // [2]
  int*  chist2 = (int*)(smem + 34856);                   // [NC]

  const int t = threadIdx.x, lane = t & 63, wv = t >> 6;
  const int s0 = blockIdx.x * 4;
  const int s = s0 + wv;
  const int qi = idxs[s];
  const float q2v = q2[s];
  const float tv = thr[s];
  const int cnt = ccount[s];

  if (lane == 0) { lflag[wv] = flag[s]; acount[wv] = 0; }
  if (lane < NC) chist[wv * NC + lane] = 0;

  bool bad = (flag[s] != 0) || (cnt < SEL) || (cnt > CAP);
  const int nc = bad ? 0 : cnt;

  if (!bad) {
    unsigned int* kw = keys + wv * CAP;
    for (int k = lane; k < nc; k += 64) kw[k] = cand[(size_t)s * CAP + k];

    unsigned int mykth = 0xFFFFFFFFu;
    for (int k = lane; k < nc; k += 64) {
      unsigned int ki = kw[k];
      int r = 0;
      for (int j = 0; j < nc; ++j) r += (kw[j] < ki) ? 1 : 0;
      if (r == SEL - 1) mykth = ki;
    }
    unsigned long long bal = __ballot(mykth != 0xFFFFFFFFu);
    int srcl = __ffsll((unsigned long long)bal) - 1;
    unsigned int kthkey = (unsigned int)__shfl((int)mykth, srcl, 64);
    float kv = h2f((unsigned short)(kthkey >> 16));

    if (kv > tv - 2.f * EPSA) {
      bad = true;
      if (lane == 0) lflag[wv] = 1;
    } else {
      const float lo = kv - 2.f * EPSA, hi = kv + 2.f * EPSA;
      int nbl = 0;
      for (int k = lane; k < nc; k += 64) {
        unsigned int ki = kw[k];
        float av = h2f((unsigned short)(ki >> 16));
        int col = (int)(ki & 0x1FFFu);
        if (av < lo) {
          ++nbl;
          atomicAdd(&chist[wv * NC + hard[col]], 1);
        } else if (av <= hi) {
          int sl = atomicAdd(&acount[wv], 1);
          if (sl < 64) ambi[wv * 64 + sl] = (unsigned int)col;
        }
      }
      #pragma unroll
      for (int o = 32; o; o >>= 1) nbl += __shfl_down(nbl, o, 64);
      int nbelow = __shfl(nbl, 0, 64);
      int na = acount[wv];
      if (na > 64) {
        bad = true;
        if (lane == 0) lflag[wv] = 1;
      } else {
        const int g = lane >> 4, sl = lane & 15;
        float4 qf[4];
        #pragma unroll
        for (int j = 0; j < 4; ++j)
          qf[j] = ((const float4*)(enc + (size_t)qi * NENC))[sl * 4 + j];
        for (int a0 = g; a0 < na; a0 += 4) {
          int col = (int)ambi[wv * 64 + a0];
          const float4* er = (const float4*)(enc + (size_t)col * NENC);
          float p = 0.f;
          #pragma unroll
          for (int j = 0; j < 4; ++j) {
            float4 ev = er[sl * 4 + j];
            p += qf[j].x * ev.x + qf[j].y * ev.y + qf[j].z * ev.z + qf[j].w * ev.w;
          }
          #pragma unroll
          for (int o2 = 1; o2 < 16; o2 <<= 1) p += __shfl_xor(p, o2, 64);
          if (sl == 0) exd[wv * 64 + a0] = sqrtf(fmaxf((q2v - 2.0f * p) + e2[col], 0.f));
        }

        int rank1 = SEL - nbelow;
        float myv = (lane < na) ? exd[wv * 64 + lane] : 1e30f;
        int rl = 0, re = 0;
        for (int j = 0; j < na; ++j) {
          float ov = exd[wv * 64 + j];
          rl += (ov < myv) ? 1 : 0;
          re += (ov == myv) ? 1 : 0;
        }
        float mykv = 1e30f;
        if (lane < na && rl <= rank1 - 1 && rank1 - 1 < rl + re) mykv = myv;
        #pragma unroll
        for (int o = 32; o; o >>= 1) mykv = fminf(mykv, __shfl_down(mykv, o, 64));
        float kthdd = __shfl(mykv, 0, 64);

        int nin = 0;
        for (int k = lane; k < na; k += 64) {
          if (exd[wv * 64 + k] < kthdd) {
            ++nin;
            atomicAdd(&chist[wv * NC + hard[(int)ambi[wv * 64 + k]]], 1);
          }
        }
        #pragma unroll
        for (int o = 32; o; o >>= 1) nin += __shfl_down(nin, o, 64);

        if (lane == 0) {
          float fn = (float)(nbelow + nin);
          float pur = 0.f;
          for (int c = 0; c < NC; ++c) {
            float p = (float)chist[wv * NC + c] / fn;
            pur -= p * logf(p + 1e-5f);
          }
          out[s] = pur * maxg[qi];
        }
      }
    }
  }

  // ---- phase 2: block-uniform brute-force for flagged rows (never expected) ----
  __syncthreads();
  int f0 = lflag[0], f1 = lflag[1], f2 = lflag[2], f3 = lflag[3];
  __syncthreads();   // all reads done before overlay reuse
  if (!(f0 | f1 | f2 | f3)) return;

  for (int r = 0; r < 4; ++r) {
    int fr = (r == 0) ? f0 : (r == 1) ? f1 : (r == 2) ? f2 : f3;
    if (!fr) continue;
    const int sf = s0 + r;
    const int qif = idxs[sf];
    qsh[t] = enc[(size_t)qif * NENC + t];
    hist[t] = 0;
    if (t < NC) chist2[t] = 0;
    __syncthreads();

    float4 q4 = ((const float4*)qsh)[lane];
    float q2f = e2[qif];
    for (int p = wv; p < NB; p += 4) {
      float4 ev = ((const float4*)(enc + (size_t)p * NENC))[lane];
      float pr = q4.x * ev.x + q4.y * ev.y + q4.z * ev.z + q4.w * ev.w;
      #pragma unroll
      for (int o = 32; o; o >>= 1) pr += __shfl_down(pr, o, 64);
      if (lane == 0) rowb[p] = sqrtf(fmaxf((q2f - 2.0f * pr) + e2[p], 0.f));
    }
    __syncthreads();

    float lmax = 0.f;
    for (int u = 0; u < 32; ++u) lmax = fmaxf(lmax, rowb[t + u * 256]);
    #pragma unroll
    for (int o = 32; o; o >>= 1) lmax = fmaxf(lmax, __shfl_down(lmax, o, 64));
    if (lane == 0) wredf[wv] = lmax;
    __syncthreads();
    float smax = fmaxf(fmaxf(wredf[0], wredf[1]), fmaxf(wredf[2], wredf[3]));
    float scale = smax > 0.f ? 256.f / smax : 0.f;

    for (int u = 0; u < 32; ++u) {
      float v = rowb[t + u * 256];
      int b = (int)(v * scale);
      b = b > 255 ? 255 : b;
      atomicAdd(&hist[b], 1);
    }
    __syncthreads();
    if (t == 0) {
      int cum = 0, j = 0;
      for (; j < 256; ++j) { cum += hist[j]; if (cum >= SEL) break; }
      if (j > 255) j = 255;
      binfo[0] = j;
      binfo[1] = SEL - (cum - hist[j]);
    }
    __syncthreads();
    const int jbin = binfo[0];
    int rank = binfo[1];

    float kth = 0.f, last = -1.f;
    bool first = true;
    for (int iter = 0; iter < 32; ++iter) {
      float lmin = INFINITY;
      for (int u = 0; u < 32; ++u) {
        float v = rowb[t + u * 256];
        bool elig;
        if (first) {
          int b = (int)(v * scale);
          b = b > 255 ? 255 : b;
          elig = (b >= jbin);
        } else {
          elig = (v > last);
        }
        if (elig) lmin = fminf(lmin, v);
      }
      #pragma unroll
      for (int o = 32; o; o >>= 1) lmin = fminf(lmin, __shfl_down(lmin, o, 64));
      __syncthreads();
      if (lane == 0) wredf[wv] = lmin;
      __syncthreads();
      float m = fminf(fminf(wredf[0], wredf[1]), fminf(wredf[2], wredf[3]));

      int lc = 0;
      for (int u = 0; u < 32; ++u) lc += (rowb[t + u * 256] == m) ? 1 : 0;
      #pragma unroll
      for (int o = 32; o; o >>= 1) lc += __shfl_down(lc, o, 64);
      __syncthreads();
      if (lane == 0) wredi[wv] = lc;
      __syncthreads();
      int c = wredi[0] + wredi[1] + wredi[2] + wredi[3];

      kth = m;
      if (c >= rank) break;
      rank -= c;
      last = m;
      first = false;
    }

    int ln = 0;
    for (int u = 0; u < 32; ++u) {
      int i = t + u * 256;
      if (rowb[i] < kth) { atomicAdd(&chist2[hard[i]], 1); ++ln; }
    }
    #pragma unroll
    for (int o = 32; o; o >>= 1) ln += __shfl_down(ln, o, 64);
    __syncthreads();
    if (lane == 0) wredi[wv] = ln;
    __syncthreads();
    if (t == 0) {
      float fn = (float)(wredi[0] + wredi[1] + wredi[2] + wredi[3]);
      float pur = 0.f;
      for (int c = 0; c < NC; ++c) {
        float p = (float)chist2[c] / fn;
        pur -= p * logf(p + 1e-5f);
      }
      out[sf] = pur * maxg[qif];
    }
    __syncthreads();
  }
}

// ---------------- launch: 4 dispatches, no memset ----------------
extern "C" void kernel_launch(void* const* d_in, const int* in_sizes, int n_in,
                              void* d_out, int out_size, void* d_ws, size_t ws_size,
                              hipStream_t stream) {
  const float* enc = (const float*)d_in[0];
  const float* cat = (const float*)d_in[1];
  const int* idxs = (const int*)d_in[2];
  float* out = (float*)d_out;

  char* ws = (char*)d_ws;
  float* e2    = (float*)ws;                  // NB
  float* maxg  = e2 + NB;                     // NB
  float* q2    = maxg + NB;                   // NS
  float* thr   = q2 + NS;                     // NS
  float* thr2  = thr + NS;                    // NS
  float* psum  = thr2 + NS;                   // 2*NPB
  int*   hard   = (int*)(psum + 2 * NPB);     // NB
  int*   ccount = hard + NB;                  // NS
  int*   flag   = ccount + NS;                // NS
  unsigned int* cand = (unsigned int*)(flag + NS);       // NS*CAP
  ushort* Abf = (ushort*)(cand + (size_t)NS * CAP);      // NS*NENC
  ushort* Bbf = Abf + (size_t)NS * NENC;                 // NB*NENC

  prep_kernel<<<dim3(NPB), dim3(256), 0, stream>>>(enc, cat, e2, maxg, hard, Bbf,
                                                   psum, ccount, flag);
  thr_kernel<<<dim3(NS / 4), dim3(256), 0, stream>>>(enc, idxs, e2, psum, Abf,
                                                     q2, thr, thr2);
  d2gemm<<<dim3(4096), dim3(256), 0, stream>>>(Abf, Bbf, q2, e2, thr2, ccount, cand, flag);
  refine_fix<<<dim3(NS / 4), dim3(256), 0, stream>>>(cand, ccount, enc, e2, q2, thr,
                                                     hard, maxg, idxs, flag, out);
}